// Round 4
// baseline (998.940 us; speedup 1.0000x reference)
//
#include <hip/hip_runtime.h>
#include <hip/hip_bf16.h>
#include <cstdint>

// ---------------------------------------------------------------------------
// Problem constants
// ---------------------------------------------------------------------------
#define B_   4
#define T_   8192
#define D_   128
#define M_   8
#define BT_  (B_*T_)          // 32768 tokens
#define NC_  256              // scan chunks (32 steps each)
#define LCH_ (T_/NC_)         // 32 steps/chunk
#define Z_OFF (BT_*D_)        // d_out: [y (BT*D)] [z (BT*D)]

// workspace layout (bytes)
#define WS_PI    256
#define WS_W12   (WS_PI  + BT_*M_*4)        // 128x1024 bf16
#define WS_W2    (WS_W12 + 128*1024*2)      // 128x2048 bf16
#define WS_S     (WS_W2  + 128*2048*2)      // chunk end-states
#define WS_ZST   (WS_S   + NC_*B_*64*2*4)   // chunk start-states
// total ~2.8 MB

typedef float f32x4 __attribute__((ext_vector_type(4)));
typedef short short8 __attribute__((ext_vector_type(8)));

__device__ __forceinline__ unsigned short f2bf(float f){
  union { float f; uint32_t u; } v; v.f = f;
  return (unsigned short)((v.u + 0x7FFFu + ((v.u >> 16) & 1u)) >> 16);
}
__device__ __forceinline__ uint32_t pk2bf(float a, float b){
  return (uint32_t)f2bf(a) | ((uint32_t)f2bf(b) << 16);
}
__device__ __forceinline__ float bflo(uint32_t p){ return __int_as_float((int)(p << 16)); }
__device__ __forceinline__ float bfhi(uint32_t p){ return __int_as_float((int)(p & 0xffff0000u)); }
__device__ __forceinline__ float sigmoidf_(float x){ return 1.0f/(1.0f + __expf(-x)); }
__device__ __forceinline__ float scale_from(const float* s8){
  float s = 1.0f;
  #pragma unroll
  for (int m=0;m<M_;m++) s = fmaxf(s, s8[m]);
  return s;
}
// butterfly add over lane bits 0,1 via DPP quad_perm (VALU-only, no DS)
__device__ __forceinline__ float dpp_red4(float x){
  x += __int_as_float(__builtin_amdgcn_mov_dpp(__float_as_int(x), 0xB1, 0xF, 0xF, 1)); // xor 1
  x += __int_as_float(__builtin_amdgcn_mov_dpp(__float_as_int(x), 0x4E, 0xF, 0xF, 1)); // xor 2
  return x;
}

// ---------------------------------------------------------------------------
// K1: gate softmax pi + weight packing (bf16)
// ---------------------------------------------------------------------------
__global__ void prep_kernel(const float* __restrict__ u,
                            const float* __restrict__ gate_w,
                            const float* __restrict__ gate_b,
                            const float* __restrict__ K12,
                            const float* __restrict__ K21,
                            const float* __restrict__ K22,
                            float* __restrict__ pi_out,
                            unsigned short* __restrict__ w12,
                            unsigned short* __restrict__ w2)
{
  int bid = blockIdx.x;
  if (bid < BT_/4) {
    int wid = threadIdx.x >> 6, lane = threadIdx.x & 63;
    int bt = bid*4 + wid;
    float2 u2 = *(const float2*)(u + bt*D_ + lane*2);
    float lg[M_];
    #pragma unroll
    for (int m=0;m<M_;m++){
      float2 g2 = *(const float2*)(gate_w + m*D_ + lane*2);
      lg[m] = u2.x*g2.x + u2.y*g2.y;
    }
    #pragma unroll
    for (int off=32; off>=1; off>>=1){
      #pragma unroll
      for (int m=0;m<M_;m++) lg[m] += __shfl_xor(lg[m], off);
    }
    #pragma unroll
    for (int m=0;m<M_;m++) lg[m] += gate_b[m];
    float mx = lg[0];
    #pragma unroll
    for (int m=1;m<M_;m++) mx = fmaxf(mx, lg[m]);
    float e[M_]; float s = 0.f;
    #pragma unroll
    for (int m=0;m<M_;m++){ e[m] = __expf(lg[m]-mx); s += e[m]; }
    float inv = 1.0f/s;
    if (lane == 0){
      float* po = pi_out + bt*M_;
      *(float4*)(po)   = make_float4(e[0]*inv,e[1]*inv,e[2]*inv,e[3]*inv);
      *(float4*)(po+4) = make_float4(e[4]*inv,e[5]*inv,e[6]*inv,e[7]*inv);
    }
  } else {
    int idx = (bid - BT_/4)*1024 + threadIdx.x*4;
    #pragma unroll
    for (int t=0;t<4;t++){
      int i = idx + t;
      if (i < 128*1024){                   // W12[s, m*128+u] = K12[m,s,u]
        int s_ = i >> 10, kk = i & 1023;
        int mm = kk >> 7, uu = kk & 127;
        w12[i] = f2bf(K12[(mm*D_ + s_)*D_ + uu]);
      } else {                             // W2[y, kk]: kk<1024 -> K22, else K21
        int j = i - 128*1024;
        int y_ = j >> 11, kk = j & 2047;
        float val;
        if (kk < 1024){ int mm = kk>>7, uu = kk&127; val = K22[(mm*D_ + y_)*D_ + uu]; }
        else { int kk2 = kk-1024; int mm = kk2>>7, ss = kk2&127; val = K21[(mm*D_ + y_)*D_ + ss]; }
        w2[j] = f2bf(val);
      }
    }
  }
}

// ---------------------------------------------------------------------------
// K2: sigma_max per expert via shifted power iteration on B = K^T K.
// 1024 threads (16 waves = 4/SIMD -> 128 arch-VGPR budget; working set ~110
// regs fits WITHOUT spill -- the r2/r3 designs overflowed the allocator's
// occupancy-driven cap and spilled to scratch, 550us of latency stalls).
// Thread (rg=tid>>2, cg=tid&3) owns row rg x cols 64*cg..+63:
// rowk fp32 [64] (64 regs), colk = K^T row rg, bf16-packed [32] (32 regs).
// Deferred normalization (every 16 iters), 2 barriers/iter, DPP reduce over
// the 2 cg lane-bits.  Final sigma = ||K x|| in fp32.
// ---------------------------------------------------------------------------
#define SIG_IT 128
// x/y vectors: 64 float4 units, padded 16B every 8 units -> conflict-free b128
__device__ __forceinline__ int padf_(int unit){ return unit*4 + (unit>>3)*4; }

__global__ __launch_bounds__(1024, 4) void sigma_kernel(
    const float* __restrict__ rho_raw, const float* __restrict__ theta,
    const float* __restrict__ K12, const float* __restrict__ K21,
    const float* __restrict__ K22, float* __restrict__ sig_out)
{
  __shared__ float xv[304], yv[304];
  __shared__ float red[1];
  const int m   = blockIdx.x;
  const int tid = threadIdx.x;
  const int rg  = tid >> 2;      // 0..255 : row index
  const int cg  = tid & 3;       // 0..3   : 64-col group
  const int c0  = cg*64;
  const bool rlow = (rg < 128), clow = (c0 < 128);

  // rotation params for this row's pair (only valid when rlow)
  float rc=0.f, rs=0.f;
  if (rlow){
    int q = rg >> 1;
    float rho = sigmoidf_(rho_raw[q]) * 0.999f;
    rc = rho*cosf(theta[q]);  rs = rho*sinf(theta[q]);
  }

  // ---- rowk[j] = K[rg][c0+j]  (fp32, 64 VGPRs)
  float rowk[64];
  if (rlow && clow) {
    int q = rg >> 1;
    float v0 = (rg&1)? rs : rc;        // col 2q
    float v1 = (rg&1)? rc : -rs;       // col 2q+1
    #pragma unroll
    for (int j=0;j<64;j++){
      int c = c0 + j;
      rowk[j] = (c == 2*q) ? v0 : ((c == 2*q+1) ? v1 : 0.0f);
    }
  } else {
    const float* base;
    if (rlow)      base = K12 + (m*128 + rg)*128       + (c0 - 128);
    else if (clow) base = K21 + (m*128 + (rg-128))*128 + c0;
    else           base = K22 + (m*128 + (rg-128))*128 + (c0 - 128);
    #pragma unroll
    for (int j4=0;j4<16;j4++){
      float4 v = *(const float4*)(base + j4*4);
      rowk[4*j4+0]=v.x; rowk[4*j4+1]=v.y; rowk[4*j4+2]=v.z; rowk[4*j4+3]=v.w;
    }
  }

  // ---- colk[k] = pack_bf16( K[c0+2k][rg], K[c0+2k+1][rg] )  (K^T row rg)
  uint32_t colk[32];
  if (rlow && clow){
    #pragma unroll
    for (int k=0;k<32;k++) colk[k] = 0u;
    int q  = rg >> 1;
    int j0 = 2*q - c0;                  // even when in range
    if (j0 >= 0 && j0 < 64){
      float e0 = (rg&1)? -rs : rc;      // K[2q][rg]
      float e1 = (rg&1)?  rc : rs;      // K[2q+1][rg]
      colk[j0>>1] = pk2bf(e0, e1);
    }
  } else {
    const float* base2; int ridx;
    if (clow)        { base2 = K21 + m*128*128; ridx = rg; }        // rg>=128 here? no: clow&&!rlow -> K12
    if (clow && !rlow)      { base2 = K12 + m*128*128; ridx = rg - 128; }
    else if (!clow && rlow) { base2 = K21 + m*128*128; ridx = rg; }
    else                    { base2 = K22 + m*128*128; ridx = rg - 128; }
    int abase = clow ? c0 : c0 - 128;
    #pragma unroll
    for (int k=0;k<32;k++){
      int a = abase + 2*k;
      float f0 = base2[a*128 + ridx];
      float f1 = base2[(a+1)*128 + ridx];
      colk[k] = pk2bf(f0, f1);
    }
  }

  // ---- init x (unnormalized)
  if (tid < 256)
    xv[padf_(tid>>2) + (tid&3)] = 1.0f + 0.25f*__sinf(0.731f*(float)tid);
  __syncthreads();

  const int xu = padf_(rg>>2) + (rg&3);   // this row's slot in xv/yv
  float cshift = 0.0f;
  for (int it=0; it<SIG_IT; ++it){
    // phase 1: y = K x
    float py = 0.f;
    #pragma unroll
    for (int j4=0;j4<16;j4++){
      float4 x4 = *(const float4*)&xv[padf_(cg*16 + j4)];
      py = fmaf(rowk[4*j4+0], x4.x, py);
      py = fmaf(rowk[4*j4+1], x4.y, py);
      py = fmaf(rowk[4*j4+2], x4.z, py);
      py = fmaf(rowk[4*j4+3], x4.w, py);
    }
    py = dpp_red4(py);
    if (cg == 0) yv[xu] = py;
    __syncthreads();
    // phase 2: x' = K^T y - cshift*x   (colk bf16)
    float px = 0.f;
    #pragma unroll
    for (int k4=0;k4<16;k4++){
      float4 y4 = *(const float4*)&yv[padf_(cg*16 + k4)];
      uint32_t p0 = colk[2*k4], p1 = colk[2*k4+1];
      px = fmaf(bflo(p0), y4.x, px);
      px = fmaf(bfhi(p0), y4.y, px);
      px = fmaf(bflo(p1), y4.z, px);
      px = fmaf(bfhi(p1), y4.w, px);
    }
    px = dpp_red4(px);
    if (cg == 0){
      float xo = xv[xu];
      xv[xu] = px - cshift*xo;
    }
    __syncthreads();
    // renormalize every 16 iters; set shift from norm growth at it==31
    if ((it & 15) == 15){
      float4 xx;
      if (tid < 64){
        xx = *(const float4*)&xv[padf_(tid)];
        float n2 = xx.x*xx.x + xx.y*xx.y + xx.z*xx.z + xx.w*xx.w;
        #pragma unroll
        for (int off=32; off>=1; off>>=1) n2 += __shfl_xor(n2, off);
        if (tid == 0) red[0] = n2;
      }
      __syncthreads();
      float n2 = red[0];
      if (it == 31) cshift = 0.45f * (cshift + exp2f(log2f(n2) * (1.0f/32.0f)));
      if (tid < 64){
        float inv = rsqrtf(n2);
        *(float4*)&xv[padf_(tid)] = make_float4(xx.x*inv, xx.y*inv, xx.z*inv, xx.w*inv);
      }
      __syncthreads();
    }
  }
  // final: sigma = ||K x||  (x normalized at the it=127 renorm; fp32 rowk)
  {
    float py = 0.f;
    #pragma unroll
    for (int j4=0;j4<16;j4++){
      float4 x4 = *(const float4*)&xv[padf_(cg*16 + j4)];
      py = fmaf(rowk[4*j4+0], x4.x, py);
      py = fmaf(rowk[4*j4+1], x4.y, py);
      py = fmaf(rowk[4*j4+2], x4.z, py);
      py = fmaf(rowk[4*j4+3], x4.w, py);
    }
    py = dpp_red4(py);
    if (cg == 0) yv[xu] = py;
    __syncthreads();
    if (tid < 64){
      float4 yy = *(const float4*)&yv[padf_(tid)];
      float n2 = yy.x*yy.x + yy.y*yy.y + yy.z*yy.z + yy.w*yy.w;
      #pragma unroll
      for (int off=32; off>=1; off>>=1) n2 += __shfl_xor(n2, off);
      if (tid == 0) sig_out[m] = sqrtf(n2);
    }
  }
}

// ---------------------------------------------------------------------------
// GEMM: out[32768x128] = A[32768xKTOT] * Wpack^T, A built on the fly:
//   kk < 1024 : A[bt,kk] = pi[bt, kk>>7] * u[bt, kk&127]
//   kk >= 1024: A[bt,kk] = pi[bt,(kk-1024)>>7] * z[bt,(kk-1024)&127]
// epilogue scales by 1/scale.  128x128 tile, 4 waves, mfma 16x16x32 bf16.
// ---------------------------------------------------------------------------
template<int KTOT, bool SECOND>
__global__ __launch_bounds__(256) void gemm_kernel(
    const float* __restrict__ u, const float* __restrict__ zsrc,
    const float* __restrict__ pi, const unsigned short* __restrict__ wpack,
    float* __restrict__ out, const float* __restrict__ sig8)
{
  float inv_s = 1.0f / scale_from(sig8);
  __shared__ unsigned short a_lds[128*64];
  __shared__ unsigned short b_lds[128*64];
  const int tid  = threadIdx.x;
  const int lane = tid & 63;
  const int wid  = tid >> 6;
  const int wr   = wid >> 1, wc = wid & 1;
  const int bt0  = blockIdx.x * 128;
  f32x4 acc[4][4];
  #pragma unroll
  for (int a=0;a<4;a++){
    #pragma unroll
    for (int b=0;b<4;b++) acc[a][b] = (f32x4){0.f,0.f,0.f,0.f};
  }
  const int r = tid >> 1, half = tid & 1;
  for (int kk0 = 0; kk0 < KTOT; kk0 += 64){
    { // A-stage (reg-staged: fp32 load, *pi, ->bf16)
      const float* src; int mm, j0;
      if (!SECOND || kk0 < 1024){ mm = kk0 >> 7; j0 = (kk0 & 127) + half*32; src = u + (bt0+r)*D_ + j0; }
      else { int k2 = kk0 - 1024; mm = k2 >> 7; j0 = (k2 & 127) + half*32; src = zsrc + (bt0+r)*D_ + j0; }
      float pv = pi[(bt0+r)*M_ + mm];
      unsigned short* dst = &a_lds[r*64 + half*32];
      #pragma unroll
      for (int i=0;i<8;i++){
        float4 v = *(const float4*)(src + i*4);
        ushort4 w;
        w.x=f2bf(v.x*pv); w.y=f2bf(v.y*pv); w.z=f2bf(v.z*pv); w.w=f2bf(v.w*pv);
        *(ushort4*)(dst + i*4) = w;
      }
      // B-stage (bf16 pack, N x K row-major = B^T layout)
      const unsigned short* srcb = wpack + r*KTOT + kk0 + half*32;
      uint4* dstb = (uint4*)&b_lds[r*64 + half*32];
      #pragma unroll
      for (int i=0;i<4;i++) dstb[i] = *(const uint4*)(srcb + i*8);
    }
    __syncthreads();
    #pragma unroll
    for (int ks=0; ks<2; ks++){
      short8 af[4], bfr[4];
      #pragma unroll
      for (int f=0; f<4; f++){
        int ar_ = wr*64 + f*16 + (lane&15);
        af[f]  = *(const short8*)&a_lds[ar_*64 + ks*32 + (lane>>4)*8];
        int bn  = wc*64 + f*16 + (lane&15);
        bfr[f] = *(const short8*)&b_lds[bn*64 + ks*32 + (lane>>4)*8];
      }
      #pragma unroll
      for (int fr=0; fr<4; fr++){
        #pragma unroll
        for (int fc=0; fc<4; fc++)
          acc[fr][fc] = __builtin_amdgcn_mfma_f32_16x16x32_bf16(af[fr], bfr[fc], acc[fr][fc], 0,0,0);
      }
    }
    __syncthreads();
  }
  #pragma unroll
  for (int fr=0; fr<4; fr++){
    #pragma unroll
    for (int fc=0; fc<4; fc++){
      #pragma unroll
      for (int rr=0; rr<4; rr++){
        int row = bt0 + wr*64 + fr*16 + (lane>>4)*4 + rr;
        int col = wc*64 + fc*16 + (lane&15);
        out[row*D_ + col] = acc[fr][fc][rr]*inv_s;
      }
    }
  }
}

// ---------------------------------------------------------------------------
// Scan: 256 independent complex recurrences (block-diag 2x2 rotations).
// 3-phase exact chunked scan, NC_=256 chunks of 32.  v is in the y-region of
// d_out (already /scale).  Reference emits carry BEFORE consuming v[t].
// ---------------------------------------------------------------------------
__global__ void scan_a(const float* __restrict__ v, const float* __restrict__ rho_raw,
                       const float* __restrict__ theta, const float* __restrict__ sig8,
                       float* __restrict__ Ssum)
{
  int b = blockIdx.x >> 8, c = blockIdx.x & 255;
  int p = threadIdx.x;
  float sc  = scale_from(sig8);
  float rho = sigmoidf_(rho_raw[p]) * 0.999f / sc;
  float th  = theta[p];
  float ar = rho*cosf(th), ai = rho*sinf(th);
  const float2* vp = (const float2*)v + (b*T_ + c*LCH_)*64 + p;
  float zx=0.f, zy=0.f;
  #pragma unroll 8
  for (int t=0; t<LCH_; ++t){
    float2 vt = vp[t*64];
    float nx = fmaf(ar, zx, fmaf(-ai, zy, vt.x));
    float ny = fmaf(ai, zx, fmaf( ar, zy, vt.y));
    zx = nx; zy = ny;
  }
  ((float2*)Ssum)[(b*NC_ + c)*64 + p] = make_float2(zx, zy);
}

__global__ void scan_b(const float* __restrict__ Ssum, float* __restrict__ Zst,
                       const float* __restrict__ rho_raw, const float* __restrict__ theta,
                       const float* __restrict__ sig8)
{
  int tid = threadIdx.x;          // 256 = B_*64
  int b = tid >> 6, p = tid & 63;
  float sc  = scale_from(sig8);
  float rho = sigmoidf_(rho_raw[p]) * 0.999f / sc;
  float th  = theta[p];
  float qr = rho*cosf(th), qi = rho*sinf(th);
  #pragma unroll
  for (int s=0;s<5;s++){ float nr = qr*qr - qi*qi; float ni = 2.f*qr*qi; qr=nr; qi=ni; } // a^32
  float Zx=0.f, Zy=0.f;
  const float2* S = (const float2*)Ssum;
  float2* Z = (float2*)Zst;
  #pragma unroll 4
  for (int c=0;c<NC_;c++){
    Z[(b*NC_+c)*64 + p] = make_float2(Zx, Zy);
    float2 s = S[(b*NC_+c)*64 + p];
    float nx = qr*Zx - qi*Zy + s.x;
    float ny = qi*Zx + qr*Zy + s.y;
    Zx = nx; Zy = ny;
  }
}

__global__ void scan_c(const float* __restrict__ v, const float* __restrict__ Zst,
                       const float* __restrict__ rho_raw, const float* __restrict__ theta,
                       const float* __restrict__ sig8, float* __restrict__ zout)
{
  int b = blockIdx.x >> 8, c = blockIdx.x & 255;
  int p = threadIdx.x;
  float sc  = scale_from(sig8);
  float rho = sigmoidf_(rho_raw[p]) * 0.999f / sc;
  float th  = theta[p];
  float ar = rho*cosf(th), ai = rho*sinf(th);
  const float2* vp = (const float2*)v + (b*T_ + c*LCH_)*64 + p;
  float2*       zp = (float2*)zout    + (b*T_ + c*LCH_)*64 + p;
  float2 z0 = ((const float2*)Zst)[(b*NC_+c)*64 + p];
  float zx = z0.x, zy = z0.y;
  #pragma unroll 8
  for (int t=0; t<LCH_; ++t){
    zp[t*64] = make_float2(zx, zy);      // emit BEFORE consuming v[t]
    float2 vt = vp[t*64];
    float nx = fmaf(ar, zx, fmaf(-ai, zy, vt.x));
    float ny = fmaf(ai, zx, fmaf( ar, zy, vt.y));
    zx = nx; zy = ny;
  }
}

// ---------------------------------------------------------------------------
extern "C" void kernel_launch(void* const* d_in, const int* in_sizes, int n_in,
                              void* d_out, int out_size, void* d_ws, size_t ws_size,
                              hipStream_t stream)
{
  const float* u       = (const float*)d_in[0];
  const float* rho_raw = (const float*)d_in[1];
  const float* theta   = (const float*)d_in[2];
  const float* K12     = (const float*)d_in[3];
  const float* K21     = (const float*)d_in[4];
  const float* K22     = (const float*)d_in[5];
  const float* gate_w  = (const float*)d_in[6];
  const float* gate_b  = (const float*)d_in[7];
  float* out = (float*)d_out;
  char*  ws  = (char*)d_ws;
  float* sig8 = (float*)ws;
  float* pi   = (float*)(ws + WS_PI);
  unsigned short* w12 = (unsigned short*)(ws + WS_W12);
  unsigned short* w2  = (unsigned short*)(ws + WS_W2);
  float* Ssum = (float*)(ws + WS_S);
  float* Zst  = (float*)(ws + WS_ZST);
  float* v    = out;            // y-region doubles as v scratch until GEMM2
  float* zout = out + Z_OFF;

  hipLaunchKernelGGL(sigma_kernel, dim3(8), dim3(1024), 0, stream,
                     rho_raw, theta, K12, K21, K22, sig8);
  hipLaunchKernelGGL(prep_kernel, dim3(BT_/4 + 384), dim3(256), 0, stream,
                     u, gate_w, gate_b, K12, K21, K22, pi, w12, w2);
  hipLaunchKernelGGL((gemm_kernel<1024,false>), dim3(256), dim3(256), 0, stream,
                     u, u, pi, w12, v, sig8);
  hipLaunchKernelGGL(scan_a, dim3(B_*NC_), dim3(64), 0, stream, v, rho_raw, theta, sig8, Ssum);
  hipLaunchKernelGGL(scan_b, dim3(1), dim3(256), 0, stream, Ssum, Zst, rho_raw, theta, sig8);
  hipLaunchKernelGGL(scan_c, dim3(B_*NC_), dim3(64), 0, stream, v, Zst, rho_raw, theta, sig8, zout);
  hipLaunchKernelGGL((gemm_kernel<2048,true>), dim3(256), dim3(256), 0, stream,
                     u, zout, pi, w2, out, sig8);
}